// Round 7
// baseline (354.983 us; speedup 1.0000x reference)
//
#include <hip/hip_runtime.h>
#include <math.h>

// Problem constants (from reference)
constexpr int N_NODES = 50000;
constexpr int N_EDGES = 800000;
constexpr int TOT_E   = N_EDGES + N_NODES;   // + self loops
constexpr int HCv     = 256;                 // H*C
constexpr int MAXD    = 256;                 // LDS logit-cache capacity per wave

typedef __attribute__((ext_vector_type(8))) short bf16x8;
typedef __attribute__((ext_vector_type(4))) float f32x4;

// ---- bf16 helpers (manual RNE, deterministic) ----
__device__ __forceinline__ unsigned short f2bf(float f) {
    unsigned int u = __float_as_uint(f);
    unsigned int r = (u + 0x7fffu + ((u >> 16) & 1u)) >> 16;
    return (unsigned short)r;
}
__device__ __forceinline__ unsigned int f2bf_pack(float lo, float hi) {
    return (unsigned int)f2bf(lo) | ((unsigned int)f2bf(hi) << 16);
}
__device__ __forceinline__ float bf2f_lo(unsigned int packed) {
    return __uint_as_float(packed << 16);
}
__device__ __forceinline__ float bf2f_hi(unsigned int packed) {
    return __uint_as_float(packed & 0xffff0000u);
}

// 8 bf16 channels += alpha * row-fragment
__device__ __forceinline__ void fma_row8(const uint4 h, float a, float* acc) {
    acc[0] = fmaf(bf2f_lo(h.x), a, acc[0]);
    acc[1] = fmaf(bf2f_hi(h.x), a, acc[1]);
    acc[2] = fmaf(bf2f_lo(h.y), a, acc[2]);
    acc[3] = fmaf(bf2f_hi(h.y), a, acc[3]);
    acc[4] = fmaf(bf2f_lo(h.z), a, acc[4]);
    acc[5] = fmaf(bf2f_hi(h.z), a, acc[5]);
    acc[6] = fmaf(bf2f_lo(h.w), a, acc[6]);
    acc[7] = fmaf(bf2f_hi(h.w), a, acc[7]);
}

// ---------------- prep: fp32 -> bf16 convert / weight transpose ----------------

__global__ void cvt_bf16_k(const float* __restrict__ in, unsigned short* __restrict__ out,
                           int n4) {
    int i = blockIdx.x * blockDim.x + threadIdx.x;
    if (i >= n4) return;
    float4 v = *reinterpret_cast<const float4*>(in + (size_t)i * 4);
    ushort4 o;
    o.x = f2bf(v.x); o.y = f2bf(v.y); o.z = f2bf(v.z); o.w = f2bf(v.w);
    *reinterpret_cast<ushort4*>(out + (size_t)i * 4) = o;
}

// WT[n][k] = bf16(W[k][n]);  W is [K][256]
__global__ void wt_k(const float* __restrict__ W, unsigned short* __restrict__ WT, int K) {
    int idx = blockIdx.x * 256 + threadIdx.x;
    if (idx >= K * 256) return;
    int k = idx >> 8, n = idx & 255;
    WT[(size_t)n * K + k] = f2bf(W[idx]);
}

// ---------------- CSR build ----------------

__global__ void count_deg_k(const int* __restrict__ ei, int* __restrict__ deg) {
    int e = blockIdx.x * blockDim.x + threadIdx.x;
    if (e >= TOT_E) return;
    int dst = (e < N_EDGES) ? ei[N_EDGES + e] : (e - N_EDGES);
    atomicAdd(&deg[dst], 1);
}

__global__ void offsets_k(const int* __restrict__ deg, int* __restrict__ start,
                          int* __restrict__ cursor, int* __restrict__ total) {
    int lane = threadIdx.x & 63;
    int node = blockIdx.x * blockDim.x + threadIdx.x;
    int d = (node < N_NODES) ? deg[node] : 0;
    int pre = d;
#pragma unroll
    for (int off = 1; off < 64; off <<= 1) {
        int v = __shfl_up(pre, off);
        if (lane >= off) pre += v;
    }
    int wtot = __shfl(pre, 63);
    int base = 0;
    if (lane == 63) base = atomicAdd(total, wtot);
    base = __shfl(base, 63);
    int my = base + pre - d;
    if (node < N_NODES) { start[node] = my; cursor[node] = my; }
}

__global__ void scatter_k(const int* __restrict__ ei, int* __restrict__ cursor,
                          int* __restrict__ colv) {
    int e = blockIdx.x * blockDim.x + threadIdx.x;
    if (e >= TOT_E) return;
    int srcv, dstv;
    if (e < N_EDGES) { srcv = ei[e]; dstv = ei[N_EDGES + e]; }
    else             { srcv = dstv = e - N_EDGES; }
    int pos = atomicAdd(&cursor[dstv], 1);
    colv[pos] = srcv;
}

// ---------------- MFMA bf16 GEMM + fused attention epilogue ----------------

template <int K>
__global__ __launch_bounds__(256) void mfma_gemm_att_k(
        const unsigned short* __restrict__ A,   // [M][K] bf16
        const unsigned short* __restrict__ BT,  // [256][K] bf16 (W transposed)
        unsigned short* __restrict__ h16,       // [M][256] bf16 out
        const float* __restrict__ att_src, const float* __restrict__ att_dst,
        float* __restrict__ a_s, float* __restrict__ a_d, int M) {
    const int lane = threadIdx.x & 63;
    const int wv = threadIdx.x >> 6;
    const int lm = lane & 15;
    const int g8 = (lane >> 4) * 8;
    const int row0 = blockIdx.y * 128 + wv * 32;
    const int n0 = blockIdx.x * 64;

    int ra0 = row0 + lm;       if (ra0 >= M) ra0 = M - 1;
    int ra1 = row0 + 16 + lm;  if (ra1 >= M) ra1 = M - 1;
    const unsigned short* pa0 = A + (size_t)ra0 * K + g8;
    const unsigned short* pa1 = A + (size_t)ra1 * K + g8;
    const unsigned short* pb  = BT + (size_t)(n0 + lm) * K + g8;

    f32x4 acc[2][4] = {};
#pragma unroll
    for (int kt = 0; kt < K; kt += 32) {
        bf16x8 a0 = *reinterpret_cast<const bf16x8*>(pa0 + kt);
        bf16x8 a1 = *reinterpret_cast<const bf16x8*>(pa1 + kt);
        bf16x8 b0 = *reinterpret_cast<const bf16x8*>(pb + kt);
        bf16x8 b1 = *reinterpret_cast<const bf16x8*>(pb + 16 * K + kt);
        bf16x8 b2 = *reinterpret_cast<const bf16x8*>(pb + 32 * K + kt);
        bf16x8 b3 = *reinterpret_cast<const bf16x8*>(pb + 48 * K + kt);
        acc[0][0] = __builtin_amdgcn_mfma_f32_16x16x32_bf16(a0, b0, acc[0][0], 0, 0, 0);
        acc[0][1] = __builtin_amdgcn_mfma_f32_16x16x32_bf16(a0, b1, acc[0][1], 0, 0, 0);
        acc[0][2] = __builtin_amdgcn_mfma_f32_16x16x32_bf16(a0, b2, acc[0][2], 0, 0, 0);
        acc[0][3] = __builtin_amdgcn_mfma_f32_16x16x32_bf16(a0, b3, acc[0][3], 0, 0, 0);
        acc[1][0] = __builtin_amdgcn_mfma_f32_16x16x32_bf16(a1, b0, acc[1][0], 0, 0, 0);
        acc[1][1] = __builtin_amdgcn_mfma_f32_16x16x32_bf16(a1, b1, acc[1][1], 0, 0, 0);
        acc[1][2] = __builtin_amdgcn_mfma_f32_16x16x32_bf16(a1, b2, acc[1][2], 0, 0, 0);
        acc[1][3] = __builtin_amdgcn_mfma_f32_16x16x32_bf16(a1, b3, acc[1][3], 0, 0, 0);
    }

    float as_c[4], ad_c[4];
#pragma unroll
    for (int j = 0; j < 4; ++j) {
        int c = n0 + j * 16 + lm;
        as_c[j] = att_src[c];
        ad_c[j] = att_dst[c];
    }
    const int head = n0 >> 7;

#pragma unroll
    for (int i = 0; i < 2; ++i) {
        float ps[4] = {}, pd[4] = {};
#pragma unroll
        for (int j = 0; j < 4; ++j)
#pragma unroll
            for (int r = 0; r < 4; ++r) {
                ps[r] += acc[i][j][r] * as_c[j];
                pd[r] += acc[i][j][r] * ad_c[j];
            }
#pragma unroll
        for (int off = 1; off < 16; off <<= 1)
#pragma unroll
            for (int r = 0; r < 4; ++r) {
                ps[r] += __shfl_xor(ps[r], off);
                pd[r] += __shfl_xor(pd[r], off);
            }
        if (lm == 0) {
            int rb = row0 + i * 16 + (lane >> 4) * 4;
#pragma unroll
            for (int r = 0; r < 4; ++r) {
                if (rb + r < M) {
                    atomicAdd(&a_s[(rb + r) * 2 + head], ps[r]);
                    atomicAdd(&a_d[(rb + r) * 2 + head], pd[r]);
                }
            }
        }
#pragma unroll
        for (int j = 0; j < 4; ++j)
#pragma unroll
            for (int r = 0; r < 4; ++r) {
                int row = row0 + i * 16 + (lane >> 4) * 4 + r;
                if (row < M)
                    h16[(size_t)row * HCv + n0 + j * 16 + lm] = f2bf(acc[i][j][r]);
            }
    }
}

// ---------------- aggregation: one wave per destination node ----------------
// Fast path: max-free softmax; pass B keeps 8 edges (4 uint4 loads/lane) in
// flight per iteration; 1/denom deferred to epilogue. FINAL fuses the 256->2
// linear + softmax (layer 1), eliminating the fp32 buffer and final kernel.

__device__ __forceinline__ float lrelu(float x) { return x > 0.f ? x : 0.2f * x; }

template <bool TANH, bool OB16, bool FINAL>
__global__ __launch_bounds__(256) void agg_k(const unsigned short* __restrict__ h16,
                      const float* __restrict__ a_s, const float* __restrict__ a_d,
                      const int* __restrict__ start, const int* __restrict__ deg,
                      const int* __restrict__ colv, const float* __restrict__ bias,
                      float* __restrict__ outf, unsigned short* __restrict__ out16,
                      const float* __restrict__ Wl, const float* __restrict__ bl) {
    __shared__ float lexp[4][MAXD][2];
    const int lane = threadIdx.x & 63;
    const int wslot = threadIdx.x >> 6;
    const int node = blockIdx.x * 4 + wslot;
    if (node >= N_NODES) return;
    const int beg = start[node];
    const int degv = deg[node];
    const float ad0 = a_d[node * 2], ad1 = a_d[node * 2 + 1];
    const int* __restrict__ col = colv + beg;

    if (degv <= MAXD) {
        // ---- pass A: gather a_s, exp (max-free), stash to LDS, sum ----
        float s0 = 0.f, s1 = 0.f;
        for (int j = lane; j < degv; j += 64) {
            int s = col[j];
            float2 av = *reinterpret_cast<const float2*>(a_s + s * 2);
            float e0 = __expf(lrelu(av.x + ad0));
            float e1 = __expf(lrelu(av.y + ad1));
            *reinterpret_cast<float2*>(&lexp[wslot][j][0]) = make_float2(e0, e1);
            s0 += e0;
            s1 += e1;
        }
#pragma unroll
        for (int off = 32; off; off >>= 1) {
            s0 += __shfl_xor(s0, off);
            s1 += __shfl_xor(s1, off);
        }
        const float inv0 = 1.f / (s0 + 1e-16f);
        const float inv1 = 1.f / (s1 + 1e-16f);

        // ---- pass B: 8 edges in flight; quarter q owns edges {i+q, i+4+q};
        // lane covers 16 channels [lq*16, lq*16+16) ----
        const int q = lane >> 4;
        const int lq = lane & 15;
        const int cb = lq * 16;
        const int head = lq >> 3;
        const float invh = head ? inv1 : inv0;
        const unsigned short* __restrict__ hp = h16 + cb;
        float acc[16] = {};
        int i = 0;
        for (; i + 8 <= degv; i += 8) {
            const int jA = i + q, jB = i + 4 + q;
            const int sA = col[jA], sB = col[jB];
            const uint4* pA = reinterpret_cast<const uint4*>(hp + (size_t)sA * HCv);
            const uint4* pB = reinterpret_cast<const uint4*>(hp + (size_t)sB * HCv);
            const uint4 a0 = pA[0];
            const uint4 a1 = pA[1];
            const uint4 b0 = pB[0];
            const uint4 b1 = pB[1];
            const float alA = lexp[wslot][jA][head];
            const float alB = lexp[wslot][jB][head];
            fma_row8(a0, alA, acc);
            fma_row8(a1, alA, acc + 8);
            fma_row8(b0, alB, acc);
            fma_row8(b1, alB, acc + 8);
        }
        for (; i < degv; i += 4) {          // <= 2 guarded tail groups
            const int j = i + q;
            if (j < degv) {
                const int s = col[j];
                const uint4* p = reinterpret_cast<const uint4*>(hp + (size_t)s * HCv);
                const uint4 h0 = p[0];
                const uint4 h1 = p[1];
                const float al = lexp[wslot][j][head];
                fma_row8(h0, al, acc);
                fma_row8(h1, al, acc + 8);
            }
        }
#pragma unroll
        for (int c = 0; c < 16; ++c) {
            acc[c] += __shfl_xor(acc[c], 16);
            acc[c] += __shfl_xor(acc[c], 32);
            acc[c] = fmaf(acc[c], invh, bias[cb + c]);
        }
        if (FINAL) {
            // fused 256->2 linear + softmax (all lanes hold their lq's sums)
            float p0 = 0.f, p1 = 0.f;
#pragma unroll
            for (int c = 0; c < 16; ++c) {
                p0 = fmaf(acc[c], Wl[(cb + c) * 2 + 0], p0);
                p1 = fmaf(acc[c], Wl[(cb + c) * 2 + 1], p1);
            }
#pragma unroll
            for (int off = 1; off < 16; off <<= 1) {
                p0 += __shfl_xor(p0, off);
                p1 += __shfl_xor(p1, off);
            }
            if (lane == 0) {
                p0 += bl[0];
                p1 += bl[1];
                float mx = fmaxf(p0, p1);
                float e0 = __expf(p0 - mx), e1 = __expf(p1 - mx);
                float inv = 1.f / (e0 + e1);
                outf[node * 2 + 0] = e0 * inv;
                outf[node * 2 + 1] = e1 * inv;
            }
        } else if (lane < 16) {
            if (TANH) {
#pragma unroll
                for (int c = 0; c < 16; ++c) acc[c] = tanhf(acc[c]);
            }
            if (OB16) {
                uint4 v0, v1;
                v0.x = f2bf_pack(acc[0], acc[1]);
                v0.y = f2bf_pack(acc[2], acc[3]);
                v0.z = f2bf_pack(acc[4], acc[5]);
                v0.w = f2bf_pack(acc[6], acc[7]);
                v1.x = f2bf_pack(acc[8], acc[9]);
                v1.y = f2bf_pack(acc[10], acc[11]);
                v1.z = f2bf_pack(acc[12], acc[13]);
                v1.w = f2bf_pack(acc[14], acc[15]);
                uint4* o = reinterpret_cast<uint4*>(out16 + (size_t)node * HCv + cb);
                o[0] = v0;
                o[1] = v1;
            } else {
                float4* o = reinterpret_cast<float4*>(outf + (size_t)node * HCv + cb);
                o[0] = make_float4(acc[0], acc[1], acc[2], acc[3]);
                o[1] = make_float4(acc[4], acc[5], acc[6], acc[7]);
                o[2] = make_float4(acc[8], acc[9], acc[10], acc[11]);
                o[3] = make_float4(acc[12], acc[13], acc[14], acc[15]);
            }
        }
    } else {
        // ---- fallback: 3-pass recompute path (deg > MAXD) ----
        const int end = beg + degv;
        float m0 = -INFINITY, m1 = -INFINITY;
        for (int e = beg + lane; e < end; e += 64) {
            int s = colv[e];
            m0 = fmaxf(m0, lrelu(a_s[s * 2] + ad0));
            m1 = fmaxf(m1, lrelu(a_s[s * 2 + 1] + ad1));
        }
#pragma unroll
        for (int off = 32; off; off >>= 1) {
            m0 = fmaxf(m0, __shfl_xor(m0, off));
            m1 = fmaxf(m1, __shfl_xor(m1, off));
        }
        float s0 = 0.f, s1 = 0.f;
        for (int e = beg + lane; e < end; e += 64) {
            int s = colv[e];
            s0 += __expf(lrelu(a_s[s * 2] + ad0) - m0);
            s1 += __expf(lrelu(a_s[s * 2 + 1] + ad1) - m1);
        }
#pragma unroll
        for (int off = 32; off; off >>= 1) {
            s0 += __shfl_xor(s0, off);
            s1 += __shfl_xor(s1, off);
        }
        float inv0 = 1.f / (s0 + 1e-16f);
        float inv1 = 1.f / (s1 + 1e-16f);
        const int head = lane >> 5;
        const float mh  = head ? m1 : m0;
        const float ih  = head ? inv1 : inv0;
        const float adh = head ? ad1 : ad0;
        const int cbase = lane * 4;
        float acc0 = 0.f, acc1 = 0.f, acc2 = 0.f, acc3 = 0.f;
        for (int e = beg; e < end; ++e) {
            int s = colv[e];
            float l = lrelu(a_s[s * 2 + head] + adh);
            float alpha = __expf(l - mh) * ih;
            uint2 hv = *reinterpret_cast<const uint2*>(h16 + (size_t)s * HCv + cbase);
            acc0 = fmaf(bf2f_lo(hv.x), alpha, acc0);
            acc1 = fmaf(bf2f_hi(hv.x), alpha, acc1);
            acc2 = fmaf(bf2f_lo(hv.y), alpha, acc2);
            acc3 = fmaf(bf2f_hi(hv.y), alpha, acc3);
        }
        float o0 = acc0 + bias[cbase + 0];
        float o1 = acc1 + bias[cbase + 1];
        float o2 = acc2 + bias[cbase + 2];
        float o3 = acc3 + bias[cbase + 3];
        if (FINAL) {
            float p0 = 0.f, p1 = 0.f;
            p0 = fmaf(o0, Wl[(cbase + 0) * 2 + 0], p0);
            p1 = fmaf(o0, Wl[(cbase + 0) * 2 + 1], p1);
            p0 = fmaf(o1, Wl[(cbase + 1) * 2 + 0], p0);
            p1 = fmaf(o1, Wl[(cbase + 1) * 2 + 1], p1);
            p0 = fmaf(o2, Wl[(cbase + 2) * 2 + 0], p0);
            p1 = fmaf(o2, Wl[(cbase + 2) * 2 + 1], p1);
            p0 = fmaf(o3, Wl[(cbase + 3) * 2 + 0], p0);
            p1 = fmaf(o3, Wl[(cbase + 3) * 2 + 1], p1);
#pragma unroll
            for (int off = 1; off < 64; off <<= 1) {
                p0 += __shfl_xor(p0, off);
                p1 += __shfl_xor(p1, off);
            }
            if (lane == 0) {
                p0 += bl[0];
                p1 += bl[1];
                float mx = fmaxf(p0, p1);
                float e0 = __expf(p0 - mx), e1 = __expf(p1 - mx);
                float inv = 1.f / (e0 + e1);
                outf[node * 2 + 0] = e0 * inv;
                outf[node * 2 + 1] = e1 * inv;
            }
        } else {
            if (TANH) {
                o0 = tanhf(o0); o1 = tanhf(o1); o2 = tanhf(o2); o3 = tanhf(o3);
            }
            if (OB16) {
                ushort4 v;
                v.x = f2bf(o0); v.y = f2bf(o1); v.z = f2bf(o2); v.w = f2bf(o3);
                *reinterpret_cast<ushort4*>(out16 + (size_t)node * HCv + cbase) = v;
            } else {
                *reinterpret_cast<float4*>(outf + (size_t)node * HCv + cbase) =
                    make_float4(o0, o1, o2, o3);
            }
        }
    }
}

// ---------------- launch ----------------

extern "C" void kernel_launch(void* const* d_in, const int* in_sizes, int n_in,
                              void* d_out, int out_size, void* d_ws, size_t ws_size,
                              hipStream_t stream) {
    const float* x        = (const float*)d_in[0];
    const int*   ei       = (const int*)d_in[1];
    const float* W0       = (const float*)d_in[2];
    const float* att_src0 = (const float*)d_in[3];
    const float* att_dst0 = (const float*)d_in[4];
    const float* b0       = (const float*)d_in[5];
    const float* W1       = (const float*)d_in[6];
    const float* att_src1 = (const float*)d_in[7];
    const float* att_dst1 = (const float*)d_in[8];
    const float* b1       = (const float*)d_in[9];
    const float* Wl       = (const float*)d_in[10];
    const float* bl       = (const float*)d_in[11];
    float* out = (float*)d_out;

    // workspace layout (no fp32 feature buffer anymore)
    unsigned short* xb     = (unsigned short*)d_ws;               // N*128 bf16
    unsigned short* h16    = xb + (size_t)N_NODES * 128;          // N*256 bf16 (gemm out)
    unsigned short* hact16 = h16 + (size_t)N_NODES * HCv;         // N*256 bf16 (layer0 agg out)
    unsigned short* WT0    = hact16 + (size_t)N_NODES * HCv;      // 256*128 bf16
    unsigned short* WT1    = WT0 + 256 * 128;                     // 256*256 bf16
    float* a_s  = (float*)(WT1 + 256 * 256);                      // N*2
    float* a_d  = a_s + N_NODES * 2;                              // N*2
    int* deg    = (int*)(a_d + N_NODES * 2);                      // N
    int* total  = deg + N_NODES;                                  // 1
    int* start  = total + 1;                                      // N
    int* cursor = start + N_NODES;                                // N
    int* colv   = cursor + N_NODES;                               // E + N

    // ---- prep: bf16 conversions ----
    cvt_bf16_k<<<(N_NODES * 128 / 4 + 255) / 256, 256, 0, stream>>>(x, xb, N_NODES * 128 / 4);
    wt_k<<<128, 256, 0, stream>>>(W0, WT0, 128);
    wt_k<<<256, 256, 0, stream>>>(W1, WT1, 256);

    // ---- CSR build ----
    hipMemsetAsync(deg, 0, (N_NODES + 1) * sizeof(int), stream);
    int eb = (TOT_E + 255) / 256;
    count_deg_k<<<eb, 256, 0, stream>>>(ei, deg);
    offsets_k<<<(N_NODES + 255) / 256, 256, 0, stream>>>(deg, start, cursor, total);
    scatter_k<<<eb, 256, 0, stream>>>(ei, cursor, colv);

    dim3 ggrid(4, (N_NODES + 127) / 128);
    int nn4 = (N_NODES + 3) / 4;

    // ---- layer 0 ----
    hipMemsetAsync(a_s, 0, (size_t)N_NODES * 4 * sizeof(float), stream);
    mfma_gemm_att_k<128><<<ggrid, 256, 0, stream>>>(xb, WT0, h16, att_src0, att_dst0,
                                                    a_s, a_d, N_NODES);
    agg_k<true, true, false><<<nn4, 256, 0, stream>>>(h16, a_s, a_d, start, deg, colv,
                                                      b0, nullptr, hact16, nullptr, nullptr);

    // ---- layer 1 (agg fused with final linear + softmax) ----
    hipMemsetAsync(a_s, 0, (size_t)N_NODES * 4 * sizeof(float), stream);
    mfma_gemm_att_k<256><<<ggrid, 256, 0, stream>>>(hact16, WT1, h16, att_src1, att_dst1,
                                                    a_s, a_d, N_NODES);
    agg_k<false, false, true><<<nn4, 256, 0, stream>>>(h16, a_s, a_d, start, deg, colv,
                                                       b1, out, nullptr, Wl, bl);
}

// Round 8
// 348.844 us; speedup vs baseline: 1.0176x; 1.0176x over previous
//
#include <hip/hip_runtime.h>
#include <math.h>

// Problem constants (from reference)
constexpr int N_NODES = 50000;
constexpr int N_EDGES = 800000;
constexpr int TOT_E   = N_EDGES + N_NODES;   // + self loops
constexpr int HCv     = 256;                 // H*C
constexpr int MAXD    = 256;                 // LDS logit-cache capacity per wave

// GEMM grid geometry (XCD-swizzled 1-D launch)
constexpr int GY         = (N_NODES + 127) / 128;  // 391 row-tiles
constexpr int GPX        = (GY + 7) / 8;           // 49 row-tiles per XCD
constexpr int GEMM_BLKS  = 8 * GPX * 4;            // 1568 (4 idle, guarded)

// prep_k section sizes
constexpr int PREP_CVT   = (N_NODES * 128 / 4 + 255) / 256;   // 6250
constexpr int PREP_WT0   = 128;                               // 128*256/256
constexpr int PREP_WT1   = 256;
constexpr int PREP_DEG   = (TOT_E + 255) / 256;               // 3321
constexpr int PREP_ZERO  = (N_NODES * 4 / 4 + 255) / 256;     // 196
constexpr int PREP_BLKS  = PREP_CVT + PREP_WT0 + PREP_WT1 + PREP_DEG + PREP_ZERO;

typedef __attribute__((ext_vector_type(8))) short bf16x8;
typedef __attribute__((ext_vector_type(4))) float f32x4;

// ---- bf16 helpers (manual RNE, deterministic) ----
__device__ __forceinline__ unsigned short f2bf(float f) {
    unsigned int u = __float_as_uint(f);
    unsigned int r = (u + 0x7fffu + ((u >> 16) & 1u)) >> 16;
    return (unsigned short)r;
}
__device__ __forceinline__ unsigned int f2bf_pack(float lo, float hi) {
    return (unsigned int)f2bf(lo) | ((unsigned int)f2bf(hi) << 16);
}
__device__ __forceinline__ float bf2f_lo(unsigned int packed) {
    return __uint_as_float(packed << 16);
}
__device__ __forceinline__ float bf2f_hi(unsigned int packed) {
    return __uint_as_float(packed & 0xffff0000u);
}

// ---------------- fused prep: cvt x, transpose W0/W1, count degrees, zero a_s/a_d ----

__global__ __launch_bounds__(256) void prep_k(const float* __restrict__ x,
                                              unsigned short* __restrict__ xb,
                                              const float* __restrict__ W0,
                                              unsigned short* __restrict__ WT0,
                                              const float* __restrict__ W1,
                                              unsigned short* __restrict__ WT1,
                                              const int* __restrict__ ei,
                                              int* __restrict__ deg,
                                              float* __restrict__ a_sd) {
    int b = blockIdx.x;
    if (b < PREP_CVT) {                       // x -> bf16 (float4 quads)
        int i = b * 256 + threadIdx.x;
        if (i < N_NODES * 128 / 4) {
            float4 v = *reinterpret_cast<const float4*>(x + (size_t)i * 4);
            ushort4 o;
            o.x = f2bf(v.x); o.y = f2bf(v.y); o.z = f2bf(v.z); o.w = f2bf(v.w);
            *reinterpret_cast<ushort4*>(xb + (size_t)i * 4) = o;
        }
        return;
    }
    b -= PREP_CVT;
    if (b < PREP_WT0) {                       // WT0[n][k] = bf16(W0[k][n]), K=128
        int idx = b * 256 + threadIdx.x;      // idx over K*256
        int k = idx >> 8, n = idx & 255;
        WT0[(size_t)n * 128 + k] = f2bf(W0[idx]);
        return;
    }
    b -= PREP_WT0;
    if (b < PREP_WT1) {                       // WT1[n][k] = bf16(W1[k][n]), K=256
        int idx = b * 256 + threadIdx.x;
        int k = idx >> 8, n = idx & 255;
        WT1[(size_t)n * 256 + k] = f2bf(W1[idx]);
        return;
    }
    b -= PREP_WT1;
    if (b < PREP_DEG) {                       // degree count
        int e = b * 256 + threadIdx.x;
        if (e < TOT_E) {
            int dst = (e < N_EDGES) ? ei[N_EDGES + e] : (e - N_EDGES);
            atomicAdd(&deg[dst], 1);
        }
        return;
    }
    b -= PREP_DEG;
    {                                         // zero a_s/a_d (N*4 floats)
        int i = b * 256 + threadIdx.x;
        if (i < N_NODES)
            *reinterpret_cast<float4*>(a_sd + (size_t)i * 4) = make_float4(0, 0, 0, 0);
    }
}

// ---------------- CSR build ----------------

__global__ void offsets_k(const int* __restrict__ deg, int* __restrict__ start,
                          int* __restrict__ cursor, int* __restrict__ total) {
    int lane = threadIdx.x & 63;
    int node = blockIdx.x * blockDim.x + threadIdx.x;
    int d = (node < N_NODES) ? deg[node] : 0;
    int pre = d;
#pragma unroll
    for (int off = 1; off < 64; off <<= 1) {
        int v = __shfl_up(pre, off);
        if (lane >= off) pre += v;
    }
    int wtot = __shfl(pre, 63);
    int base = 0;
    if (lane == 63) base = atomicAdd(total, wtot);
    base = __shfl(base, 63);
    int my = base + pre - d;
    if (node < N_NODES) { start[node] = my; cursor[node] = my; }
}

__global__ void scatter_k(const int* __restrict__ ei, int* __restrict__ cursor,
                          int* __restrict__ colv) {
    int e = blockIdx.x * blockDim.x + threadIdx.x;
    if (e >= TOT_E) return;
    int srcv, dstv;
    if (e < N_EDGES) { srcv = ei[e]; dstv = ei[N_EDGES + e]; }
    else             { srcv = dstv = e - N_EDGES; }
    int pos = atomicAdd(&cursor[dstv], 1);
    colv[pos] = srcv;
}

// ---------------- MFMA bf16 GEMM + fused attention epilogue ----------------
// 1-D grid, XCD-aware swizzle: the 4 col-blocks sharing one 128-row A-tile
// land on the SAME XCD (dispatch round-robins blockIdx across 8 XCDs), so an
// A-tile is fetched into one L2 once instead of 4x.

template <int K>
__global__ __launch_bounds__(256) void mfma_gemm_att_k(
        const unsigned short* __restrict__ A,   // [M][K] bf16
        const unsigned short* __restrict__ BT,  // [256][K] bf16 (W transposed)
        unsigned short* __restrict__ h16,       // [M][256] bf16 out
        const float* __restrict__ att_src, const float* __restrict__ att_dst,
        float* __restrict__ a_s, float* __restrict__ a_d, int M) {
    // swizzle: bid = (xcd) + 8*(k + 4*gy_idx)  ->  gy = xcd + 8*gy_idx
    const int bid = blockIdx.x;
    const int xcd = bid & 7;
    const int t   = bid >> 3;
    const int kx  = t & 3;
    const int gy  = xcd + 8 * (t >> 2);
    if (gy >= GY) return;

    const int lane = threadIdx.x & 63;
    const int wv = threadIdx.x >> 6;
    const int lm = lane & 15;
    const int g8 = (lane >> 4) * 8;
    const int row0 = gy * 128 + wv * 32;
    const int n0 = kx * 64;

    int ra0 = row0 + lm;       if (ra0 >= M) ra0 = M - 1;
    int ra1 = row0 + 16 + lm;  if (ra1 >= M) ra1 = M - 1;
    const unsigned short* pa0 = A + (size_t)ra0 * K + g8;
    const unsigned short* pa1 = A + (size_t)ra1 * K + g8;
    const unsigned short* pb  = BT + (size_t)(n0 + lm) * K + g8;

    f32x4 acc[2][4] = {};
#pragma unroll
    for (int kt = 0; kt < K; kt += 32) {
        bf16x8 a0 = *reinterpret_cast<const bf16x8*>(pa0 + kt);
        bf16x8 a1 = *reinterpret_cast<const bf16x8*>(pa1 + kt);
        bf16x8 b0 = *reinterpret_cast<const bf16x8*>(pb + kt);
        bf16x8 b1 = *reinterpret_cast<const bf16x8*>(pb + 16 * K + kt);
        bf16x8 b2 = *reinterpret_cast<const bf16x8*>(pb + 32 * K + kt);
        bf16x8 b3 = *reinterpret_cast<const bf16x8*>(pb + 48 * K + kt);
        acc[0][0] = __builtin_amdgcn_mfma_f32_16x16x32_bf16(a0, b0, acc[0][0], 0, 0, 0);
        acc[0][1] = __builtin_amdgcn_mfma_f32_16x16x32_bf16(a0, b1, acc[0][1], 0, 0, 0);
        acc[0][2] = __builtin_amdgcn_mfma_f32_16x16x32_bf16(a0, b2, acc[0][2], 0, 0, 0);
        acc[0][3] = __builtin_amdgcn_mfma_f32_16x16x32_bf16(a0, b3, acc[0][3], 0, 0, 0);
        acc[1][0] = __builtin_amdgcn_mfma_f32_16x16x32_bf16(a1, b0, acc[1][0], 0, 0, 0);
        acc[1][1] = __builtin_amdgcn_mfma_f32_16x16x32_bf16(a1, b1, acc[1][1], 0, 0, 0);
        acc[1][2] = __builtin_amdgcn_mfma_f32_16x16x32_bf16(a1, b2, acc[1][2], 0, 0, 0);
        acc[1][3] = __builtin_amdgcn_mfma_f32_16x16x32_bf16(a1, b3, acc[1][3], 0, 0, 0);
    }

    float as_c[4], ad_c[4];
#pragma unroll
    for (int j = 0; j < 4; ++j) {
        int c = n0 + j * 16 + lm;
        as_c[j] = att_src[c];
        ad_c[j] = att_dst[c];
    }
    const int head = n0 >> 7;

#pragma unroll
    for (int i = 0; i < 2; ++i) {
        float ps[4] = {}, pd[4] = {};
#pragma unroll
        for (int j = 0; j < 4; ++j)
#pragma unroll
            for (int r = 0; r < 4; ++r) {
                ps[r] += acc[i][j][r] * as_c[j];
                pd[r] += acc[i][j][r] * ad_c[j];
            }
#pragma unroll
        for (int off = 1; off < 16; off <<= 1)
#pragma unroll
            for (int r = 0; r < 4; ++r) {
                ps[r] += __shfl_xor(ps[r], off);
                pd[r] += __shfl_xor(pd[r], off);
            }
        if (lm == 0) {
            int rb = row0 + i * 16 + (lane >> 4) * 4;
#pragma unroll
            for (int r = 0; r < 4; ++r) {
                if (rb + r < M) {
                    atomicAdd(&a_s[(rb + r) * 2 + head], ps[r]);
                    atomicAdd(&a_d[(rb + r) * 2 + head], pd[r]);
                }
            }
        }
#pragma unroll
        for (int j = 0; j < 4; ++j)
#pragma unroll
            for (int r = 0; r < 4; ++r) {
                int row = row0 + i * 16 + (lane >> 4) * 4 + r;
                if (row < M)
                    h16[(size_t)row * HCv + n0 + j * 16 + lm] = f2bf(acc[i][j][r]);
            }
    }
}

// ---------------- aggregation: one wave per destination node ----------------
// R6-proven structure: max-free softmax, fused gather+exp pass, pass B at
// 4 edges/iter (quarter-wave x 2 uint4). FINAL fuses the 256->2 linear+softmax.

__device__ __forceinline__ float lrelu(float x) { return x > 0.f ? x : 0.2f * x; }

template <bool TANH, bool OB16, bool FINAL>
__global__ __launch_bounds__(256) void agg_k(const unsigned short* __restrict__ h16,
                      const float* __restrict__ a_s, const float* __restrict__ a_d,
                      const int* __restrict__ start, const int* __restrict__ deg,
                      const int* __restrict__ colv, const float* __restrict__ bias,
                      float* __restrict__ outf, unsigned short* __restrict__ out16,
                      const float* __restrict__ Wl, const float* __restrict__ bl) {
    __shared__ float lexp[4][MAXD][2];
    const int lane = threadIdx.x & 63;
    const int wslot = threadIdx.x >> 6;
    const int node = blockIdx.x * 4 + wslot;
    if (node >= N_NODES) return;
    const int beg = start[node];
    const int degv = deg[node];
    const float ad0 = a_d[node * 2], ad1 = a_d[node * 2 + 1];
    const int* __restrict__ col = colv + beg;

    if (degv <= MAXD) {
        // ---- pass A: gather a_s, exp (max-free), stash to LDS, sum ----
        float s0 = 0.f, s1 = 0.f;
        for (int j = lane; j < degv; j += 64) {
            int s = col[j];
            float2 av = *reinterpret_cast<const float2*>(a_s + s * 2);
            float e0 = __expf(lrelu(av.x + ad0));
            float e1 = __expf(lrelu(av.y + ad1));
            *reinterpret_cast<float2*>(&lexp[wslot][j][0]) = make_float2(e0, e1);
            s0 += e0;
            s1 += e1;
        }
#pragma unroll
        for (int off = 32; off; off >>= 1) {
            s0 += __shfl_xor(s0, off);
            s1 += __shfl_xor(s1, off);
        }
        const float inv0 = 1.f / (s0 + 1e-16f);
        const float inv1 = 1.f / (s1 + 1e-16f);

        // ---- pass B: 4 edges/iter; quarter q owns edge 4i+q; lane covers
        // 16 channels [lq*16, lq*16+16) (single head per lane) ----
        const int q = lane >> 4;
        const int lq = lane & 15;
        const int cb = lq * 16;
        const int head = lq >> 3;
        const float invh = head ? inv1 : inv0;
        const unsigned short* __restrict__ hp = h16 + cb;
        float acc[16] = {};
        const int full = degv >> 2;
        for (int i = 0; i < full; ++i) {
            const int j = 4 * i + q;
            const int s = col[j];
            const float alpha = lexp[wslot][j][head] * invh;
            const uint4* p = reinterpret_cast<const uint4*>(hp + (size_t)s * HCv);
            const uint4 h0 = p[0];
            const uint4 h1 = p[1];
            acc[0]  = fmaf(bf2f_lo(h0.x), alpha, acc[0]);
            acc[1]  = fmaf(bf2f_hi(h0.x), alpha, acc[1]);
            acc[2]  = fmaf(bf2f_lo(h0.y), alpha, acc[2]);
            acc[3]  = fmaf(bf2f_hi(h0.y), alpha, acc[3]);
            acc[4]  = fmaf(bf2f_lo(h0.z), alpha, acc[4]);
            acc[5]  = fmaf(bf2f_hi(h0.z), alpha, acc[5]);
            acc[6]  = fmaf(bf2f_lo(h0.w), alpha, acc[6]);
            acc[7]  = fmaf(bf2f_hi(h0.w), alpha, acc[7]);
            acc[8]  = fmaf(bf2f_lo(h1.x), alpha, acc[8]);
            acc[9]  = fmaf(bf2f_hi(h1.x), alpha, acc[9]);
            acc[10] = fmaf(bf2f_lo(h1.y), alpha, acc[10]);
            acc[11] = fmaf(bf2f_hi(h1.y), alpha, acc[11]);
            acc[12] = fmaf(bf2f_lo(h1.z), alpha, acc[12]);
            acc[13] = fmaf(bf2f_hi(h1.z), alpha, acc[13]);
            acc[14] = fmaf(bf2f_lo(h1.w), alpha, acc[14]);
            acc[15] = fmaf(bf2f_hi(h1.w), alpha, acc[15]);
        }
        {   // tail (degv & 3 edges)
            const int j = full * 4 + q;
            if (j < degv) {
                const int s = col[j];
                const float alpha = lexp[wslot][j][head] * invh;
                const uint4* p = reinterpret_cast<const uint4*>(hp + (size_t)s * HCv);
                const uint4 h0 = p[0];
                const uint4 h1 = p[1];
                acc[0]  = fmaf(bf2f_lo(h0.x), alpha, acc[0]);
                acc[1]  = fmaf(bf2f_hi(h0.x), alpha, acc[1]);
                acc[2]  = fmaf(bf2f_lo(h0.y), alpha, acc[2]);
                acc[3]  = fmaf(bf2f_hi(h0.y), alpha, acc[3]);
                acc[4]  = fmaf(bf2f_lo(h0.z), alpha, acc[4]);
                acc[5]  = fmaf(bf2f_hi(h0.z), alpha, acc[5]);
                acc[6]  = fmaf(bf2f_lo(h0.w), alpha, acc[6]);
                acc[7]  = fmaf(bf2f_hi(h0.w), alpha, acc[7]);
                acc[8]  = fmaf(bf2f_lo(h1.x), alpha, acc[8]);
                acc[9]  = fmaf(bf2f_hi(h1.x), alpha, acc[9]);
                acc[10] = fmaf(bf2f_lo(h1.y), alpha, acc[10]);
                acc[11] = fmaf(bf2f_hi(h1.y), alpha, acc[11]);
                acc[12] = fmaf(bf2f_lo(h1.z), alpha, acc[12]);
                acc[13] = fmaf(bf2f_hi(h1.z), alpha, acc[13]);
                acc[14] = fmaf(bf2f_lo(h1.w), alpha, acc[14]);
                acc[15] = fmaf(bf2f_hi(h1.w), alpha, acc[15]);
            }
        }
#pragma unroll
        for (int c = 0; c < 16; ++c) {
            acc[c] += __shfl_xor(acc[c], 16);
            acc[c] += __shfl_xor(acc[c], 32);
            acc[c] += bias[cb + c];
        }
        if (FINAL) {
            // fused 256->2 linear + softmax (all lanes hold their lq's sums)
            float p0 = 0.f, p1 = 0.f;
#pragma unroll
            for (int c = 0; c < 16; ++c) {
                p0 = fmaf(acc[c], Wl[(cb + c) * 2 + 0], p0);
                p1 = fmaf(acc[c], Wl[(cb + c) * 2 + 1], p1);
            }
#pragma unroll
            for (int off = 1; off < 16; off <<= 1) {
                p0 += __shfl_xor(p0, off);
                p1 += __shfl_xor(p1, off);
            }
            if (lane == 0) {
                p0 += bl[0];
                p1 += bl[1];
                float mx = fmaxf(p0, p1);
                float e0 = __expf(p0 - mx), e1 = __expf(p1 - mx);
                float inv = 1.f / (e0 + e1);
                outf[node * 2 + 0] = e0 * inv;
                outf[node * 2 + 1] = e1 * inv;
            }
        } else if (lane < 16) {
            if (TANH) {
#pragma unroll
                for (int c = 0; c < 16; ++c) acc[c] = tanhf(acc[c]);
            }
            if (OB16) {
                uint4 v0, v1;
                v0.x = f2bf_pack(acc[0], acc[1]);
                v0.y = f2bf_pack(acc[2], acc[3]);
                v0.z = f2bf_pack(acc[4], acc[5]);
                v0.w = f2bf_pack(acc[6], acc[7]);
                v1.x = f2bf_pack(acc[8], acc[9]);
                v1.y = f2bf_pack(acc[10], acc[11]);
                v1.z = f2bf_pack(acc[12], acc[13]);
                v1.w = f2bf_pack(acc[14], acc[15]);
                uint4* o = reinterpret_cast<uint4*>(out16 + (size_t)node * HCv + cb);
                o[0] = v0;
                o[1] = v1;
            } else {
                float4* o = reinterpret_cast<float4*>(outf + (size_t)node * HCv + cb);
                o[0] = make_float4(acc[0], acc[1], acc[2], acc[3]);
                o[1] = make_float4(acc[4], acc[5], acc[6], acc[7]);
                o[2] = make_float4(acc[8], acc[9], acc[10], acc[11]);
                o[3] = make_float4(acc[12], acc[13], acc[14], acc[15]);
            }
        }
    } else {
        // ---- fallback: 3-pass recompute path (deg > MAXD) ----
        const int end = beg + degv;
        float m0 = -INFINITY, m1 = -INFINITY;
        for (int e = beg + lane; e < end; e += 64) {
            int s = colv[e];
            m0 = fmaxf(m0, lrelu(a_s[s * 2] + ad0));
            m1 = fmaxf(m1, lrelu(a_s[s * 2 + 1] + ad1));
        }
#pragma unroll
        for (int off = 32; off; off >>= 1) {
            m0 = fmaxf(m0, __shfl_xor(m0, off));
            m1 = fmaxf(m1, __shfl_xor(m1, off));
        }
        float s0 = 0.f, s1 = 0.f;
        for (int e = beg + lane; e < end; e += 64) {
            int s = colv[e];
            s0 += __expf(lrelu(a_s[s * 2] + ad0) - m0);
            s1 += __expf(lrelu(a_s[s * 2 + 1] + ad1) - m1);
        }
#pragma unroll
        for (int off = 32; off; off >>= 1) {
            s0 += __shfl_xor(s0, off);
            s1 += __shfl_xor(s1, off);
        }
        float inv0 = 1.f / (s0 + 1e-16f);
        float inv1 = 1.f / (s1 + 1e-16f);
        const int head = lane >> 5;
        const float mh  = head ? m1 : m0;
        const float ih  = head ? inv1 : inv0;
        const float adh = head ? ad1 : ad0;
        const int cbase = lane * 4;
        float acc0 = 0.f, acc1 = 0.f, acc2 = 0.f, acc3 = 0.f;
        for (int e = beg; e < end; ++e) {
            int s = colv[e];
            float l = lrelu(a_s[s * 2 + head] + adh);
            float alpha = __expf(l - mh) * ih;
            uint2 hv = *reinterpret_cast<const uint2*>(h16 + (size_t)s * HCv + cbase);
            acc0 = fmaf(bf2f_lo(hv.x), alpha, acc0);
            acc1 = fmaf(bf2f_hi(hv.x), alpha, acc1);
            acc2 = fmaf(bf2f_lo(hv.y), alpha, acc2);
            acc3 = fmaf(bf2f_hi(hv.y), alpha, acc3);
        }
        float o0 = acc0 + bias[cbase + 0];
        float o1 = acc1 + bias[cbase + 1];
        float o2 = acc2 + bias[cbase + 2];
        float o3 = acc3 + bias[cbase + 3];
        if (FINAL) {
            float p0 = 0.f, p1 = 0.f;
            p0 = fmaf(o0, Wl[(cbase + 0) * 2 + 0], p0);
            p1 = fmaf(o0, Wl[(cbase + 0) * 2 + 1], p1);
            p0 = fmaf(o1, Wl[(cbase + 1) * 2 + 0], p0);
            p1 = fmaf(o1, Wl[(cbase + 1) * 2 + 1], p1);
            p0 = fmaf(o2, Wl[(cbase + 2) * 2 + 0], p0);
            p1 = fmaf(o2, Wl[(cbase + 2) * 2 + 1], p1);
            p0 = fmaf(o3, Wl[(cbase + 3) * 2 + 0], p0);
            p1 = fmaf(o3, Wl[(cbase + 3) * 2 + 1], p1);
#pragma unroll
            for (int off = 1; off < 64; off <<= 1) {
                p0 += __shfl_xor(p0, off);
                p1 += __shfl_xor(p1, off);
            }
            if (lane == 0) {
                p0 += bl[0];
                p1 += bl[1];
                float mx = fmaxf(p0, p1);
                float e0 = __expf(p0 - mx), e1 = __expf(p1 - mx);
                float inv = 1.f / (e0 + e1);
                outf[node * 2 + 0] = e0 * inv;
                outf[node * 2 + 1] = e1 * inv;
            }
        } else {
            if (TANH) {
                o0 = tanhf(o0); o1 = tanhf(o1); o2 = tanhf(o2); o3 = tanhf(o3);
            }
            if (OB16) {
                ushort4 v;
                v.x = f2bf(o0); v.y = f2bf(o1); v.z = f2bf(o2); v.w = f2bf(o3);
                *reinterpret_cast<ushort4*>(out16 + (size_t)node * HCv + cbase) = v;
            } else {
                *reinterpret_cast<float4*>(outf + (size_t)node * HCv + cbase) =
                    make_float4(o0, o1, o2, o3);
            }
        }
    }
}

// ---------------- launch ----------------

extern "C" void kernel_launch(void* const* d_in, const int* in_sizes, int n_in,
                              void* d_out, int out_size, void* d_ws, size_t ws_size,
                              hipStream_t stream) {
    const float* x        = (const float*)d_in[0];
    const int*   ei       = (const int*)d_in[1];
    const float* W0       = (const float*)d_in[2];
    const float* att_src0 = (const float*)d_in[3];
    const float* att_dst0 = (const float*)d_in[4];
    const float* b0       = (const float*)d_in[5];
    const float* W1       = (const float*)d_in[6];
    const float* att_src1 = (const float*)d_in[7];
    const float* att_dst1 = (const float*)d_in[8];
    const float* b1       = (const float*)d_in[9];
    const float* Wl       = (const float*)d_in[10];
    const float* bl       = (const float*)d_in[11];
    float* out = (float*)d_out;

    // workspace layout
    unsigned short* xb     = (unsigned short*)d_ws;               // N*128 bf16
    unsigned short* h16    = xb + (size_t)N_NODES * 128;          // N*256 bf16 (gemm out)
    unsigned short* hact16 = h16 + (size_t)N_NODES * HCv;         // N*256 bf16 (layer0 agg out)
    unsigned short* WT0    = hact16 + (size_t)N_NODES * HCv;      // 256*128 bf16
    unsigned short* WT1    = WT0 + 256 * 128;                     // 256*256 bf16
    float* a_s  = (float*)(WT1 + 256 * 256);                      // N*2
    float* a_d  = a_s + N_NODES * 2;                              // N*2
    int* deg    = (int*)(a_d + N_NODES * 2);                      // N
    int* total  = deg + N_NODES;                                  // 1
    int* start  = total + 1;                                      // N
    int* cursor = start + N_NODES;                                // N
    int* colv   = cursor + N_NODES;                               // E + N

    // ---- fused prep (cvt x, WT0/WT1, degree count, zero a_s/a_d) ----
    hipMemsetAsync(deg, 0, (N_NODES + 1) * sizeof(int), stream);  // deg + total
    prep_k<<<PREP_BLKS, 256, 0, stream>>>(x, xb, W0, WT0, W1, WT1, ei, deg, a_s);

    // ---- CSR offsets + scatter ----
    offsets_k<<<(N_NODES + 255) / 256, 256, 0, stream>>>(deg, start, cursor, total);
    scatter_k<<<(TOT_E + 255) / 256, 256, 0, stream>>>(ei, cursor, colv);

    int nn4 = (N_NODES + 3) / 4;

    // ---- layer 0 ----
    mfma_gemm_att_k<128><<<GEMM_BLKS, 256, 0, stream>>>(xb, WT0, h16, att_src0, att_dst0,
                                                        a_s, a_d, N_NODES);
    agg_k<true, true, false><<<nn4, 256, 0, stream>>>(h16, a_s, a_d, start, deg, colv,
                                                      b0, nullptr, hact16, nullptr, nullptr);

    // ---- layer 1 (agg fused with final linear + softmax) ----
    hipMemsetAsync(a_s, 0, (size_t)N_NODES * 4 * sizeof(float), stream);
    mfma_gemm_att_k<256><<<GEMM_BLKS, 256, 0, stream>>>(hact16, WT1, h16, att_src1, att_dst1,
                                                        a_s, a_d, N_NODES);
    agg_k<false, false, true><<<nn4, 256, 0, stream>>>(h16, a_s, a_d, start, deg, colv,
                                                       b1, out, nullptr, Wl, bl);
}

// Round 9
// 336.640 us; speedup vs baseline: 1.0545x; 1.0363x over previous
//
#include <hip/hip_runtime.h>
#include <math.h>

// Problem constants (from reference)
constexpr int N_NODES = 50000;
constexpr int N_EDGES = 800000;
constexpr int TOT_E   = N_EDGES + N_NODES;   // + self loops
constexpr int HCv     = 256;                 // H*C
constexpr int MAXD    = 256;                 // LDS logit-cache capacity per wave

// prep_k section sizes
constexpr int PREP_CVT   = (N_NODES * 128 / 4 + 255) / 256;   // 6250
constexpr int PREP_WT0   = 128;
constexpr int PREP_WT1   = 256;
constexpr int PREP_DEG   = (TOT_E + 255) / 256;               // 3321
constexpr int PREP_ZERO  = (N_NODES + 255) / 256;             // 196 (float4/thread)
constexpr int PREP_BLKS  = PREP_CVT + PREP_WT0 + PREP_WT1 + PREP_DEG + PREP_ZERO;

typedef __attribute__((ext_vector_type(8))) short bf16x8;
typedef __attribute__((ext_vector_type(4))) float f32x4;

// ---- bf16 helpers (manual RNE, deterministic) ----
__device__ __forceinline__ unsigned short f2bf(float f) {
    unsigned int u = __float_as_uint(f);
    unsigned int r = (u + 0x7fffu + ((u >> 16) & 1u)) >> 16;
    return (unsigned short)r;
}
__device__ __forceinline__ unsigned int f2bf_pack(float lo, float hi) {
    return (unsigned int)f2bf(lo) | ((unsigned int)f2bf(hi) << 16);
}
__device__ __forceinline__ float bf2f_lo(unsigned int packed) {
    return __uint_as_float(packed << 16);
}
__device__ __forceinline__ float bf2f_hi(unsigned int packed) {
    return __uint_as_float(packed & 0xffff0000u);
}

// ---------------- fused prep: cvt x, transpose W0/W1, count degrees, zero a_s/a_d ----

__global__ __launch_bounds__(256) void prep_k(const float* __restrict__ x,
                                              unsigned short* __restrict__ xb,
                                              const float* __restrict__ W0,
                                              unsigned short* __restrict__ WT0,
                                              const float* __restrict__ W1,
                                              unsigned short* __restrict__ WT1,
                                              const int* __restrict__ ei,
                                              int* __restrict__ deg,
                                              float* __restrict__ a_sd) {
    int b = blockIdx.x;
    if (b < PREP_CVT) {                       // x -> bf16 (float4 quads)
        int i = b * 256 + threadIdx.x;
        if (i < N_NODES * 128 / 4) {
            float4 v = *reinterpret_cast<const float4*>(x + (size_t)i * 4);
            ushort4 o;
            o.x = f2bf(v.x); o.y = f2bf(v.y); o.z = f2bf(v.z); o.w = f2bf(v.w);
            *reinterpret_cast<ushort4*>(xb + (size_t)i * 4) = o;
        }
        return;
    }
    b -= PREP_CVT;
    if (b < PREP_WT0) {                       // WT0[n][k] = bf16(W0[k][n]), K=128
        int idx = b * 256 + threadIdx.x;
        int k = idx >> 8, n = idx & 255;
        WT0[(size_t)n * 128 + k] = f2bf(W0[idx]);
        return;
    }
    b -= PREP_WT0;
    if (b < PREP_WT1) {                       // WT1[n][k] = bf16(W1[k][n]), K=256
        int idx = b * 256 + threadIdx.x;
        int k = idx >> 8, n = idx & 255;
        WT1[(size_t)n * 256 + k] = f2bf(W1[idx]);
        return;
    }
    b -= PREP_WT1;
    if (b < PREP_DEG) {                       // degree count
        int e = b * 256 + threadIdx.x;
        if (e < TOT_E) {
            int dst = (e < N_EDGES) ? ei[N_EDGES + e] : (e - N_EDGES);
            atomicAdd(&deg[dst], 1);
        }
        return;
    }
    b -= PREP_DEG;
    {                                         // zero a_s/a_d (N*4 floats)
        int i = b * 256 + threadIdx.x;
        if (i < N_NODES)
            *reinterpret_cast<float4*>(a_sd + (size_t)i * 4) = make_float4(0, 0, 0, 0);
    }
}

// ---------------- CSR build ----------------

__global__ void offsets_k(const int* __restrict__ deg, int* __restrict__ start,
                          int* __restrict__ cursor, int* __restrict__ total) {
    int lane = threadIdx.x & 63;
    int node = blockIdx.x * blockDim.x + threadIdx.x;
    int d = (node < N_NODES) ? deg[node] : 0;
    int pre = d;
#pragma unroll
    for (int off = 1; off < 64; off <<= 1) {
        int v = __shfl_up(pre, off);
        if (lane >= off) pre += v;
    }
    int wtot = __shfl(pre, 63);
    int base = 0;
    if (lane == 63) base = atomicAdd(total, wtot);
    base = __shfl(base, 63);
    int my = base + pre - d;
    if (node < N_NODES) { start[node] = my; cursor[node] = my; }
}

__global__ void scatter_k(const int* __restrict__ ei, int* __restrict__ cursor,
                          int* __restrict__ colv) {
    int e = blockIdx.x * blockDim.x + threadIdx.x;
    if (e >= TOT_E) return;
    int srcv, dstv;
    if (e < N_EDGES) { srcv = ei[e]; dstv = ei[N_EDGES + e]; }
    else             { srcv = dstv = e - N_EDGES; }
    int pos = atomicAdd(&cursor[dstv], 1);
    colv[pos] = srcv;
}

// ---------------- MFMA bf16 GEMM + fused attention epilogue (R6 form) ----------------

template <int K>
__global__ __launch_bounds__(256) void mfma_gemm_att_k(
        const unsigned short* __restrict__ A,   // [M][K] bf16
        const unsigned short* __restrict__ BT,  // [256][K] bf16 (W transposed)
        unsigned short* __restrict__ h16,       // [M][256] bf16 out
        const float* __restrict__ att_src, const float* __restrict__ att_dst,
        float* __restrict__ a_s, float* __restrict__ a_d, int M) {
    const int lane = threadIdx.x & 63;
    const int wv = threadIdx.x >> 6;
    const int lm = lane & 15;
    const int g8 = (lane >> 4) * 8;
    const int row0 = blockIdx.y * 128 + wv * 32;
    const int n0 = blockIdx.x * 64;

    int ra0 = row0 + lm;       if (ra0 >= M) ra0 = M - 1;
    int ra1 = row0 + 16 + lm;  if (ra1 >= M) ra1 = M - 1;
    const unsigned short* pa0 = A + (size_t)ra0 * K + g8;
    const unsigned short* pa1 = A + (size_t)ra1 * K + g8;
    const unsigned short* pb  = BT + (size_t)(n0 + lm) * K + g8;

    f32x4 acc[2][4] = {};
#pragma unroll
    for (int kt = 0; kt < K; kt += 32) {
        bf16x8 a0 = *reinterpret_cast<const bf16x8*>(pa0 + kt);
        bf16x8 a1 = *reinterpret_cast<const bf16x8*>(pa1 + kt);
        bf16x8 b0 = *reinterpret_cast<const bf16x8*>(pb + kt);
        bf16x8 b1 = *reinterpret_cast<const bf16x8*>(pb + 16 * K + kt);
        bf16x8 b2 = *reinterpret_cast<const bf16x8*>(pb + 32 * K + kt);
        bf16x8 b3 = *reinterpret_cast<const bf16x8*>(pb + 48 * K + kt);
        acc[0][0] = __builtin_amdgcn_mfma_f32_16x16x32_bf16(a0, b0, acc[0][0], 0, 0, 0);
        acc[0][1] = __builtin_amdgcn_mfma_f32_16x16x32_bf16(a0, b1, acc[0][1], 0, 0, 0);
        acc[0][2] = __builtin_amdgcn_mfma_f32_16x16x32_bf16(a0, b2, acc[0][2], 0, 0, 0);
        acc[0][3] = __builtin_amdgcn_mfma_f32_16x16x32_bf16(a0, b3, acc[0][3], 0, 0, 0);
        acc[1][0] = __builtin_amdgcn_mfma_f32_16x16x32_bf16(a1, b0, acc[1][0], 0, 0, 0);
        acc[1][1] = __builtin_amdgcn_mfma_f32_16x16x32_bf16(a1, b1, acc[1][1], 0, 0, 0);
        acc[1][2] = __builtin_amdgcn_mfma_f32_16x16x32_bf16(a1, b2, acc[1][2], 0, 0, 0);
        acc[1][3] = __builtin_amdgcn_mfma_f32_16x16x32_bf16(a1, b3, acc[1][3], 0, 0, 0);
    }

    float as_c[4], ad_c[4];
#pragma unroll
    for (int j = 0; j < 4; ++j) {
        int c = n0 + j * 16 + lm;
        as_c[j] = att_src[c];
        ad_c[j] = att_dst[c];
    }
    const int head = n0 >> 7;

#pragma unroll
    for (int i = 0; i < 2; ++i) {
        float ps[4] = {}, pd[4] = {};
#pragma unroll
        for (int j = 0; j < 4; ++j)
#pragma unroll
            for (int r = 0; r < 4; ++r) {
                ps[r] += acc[i][j][r] * as_c[j];
                pd[r] += acc[i][j][r] * ad_c[j];
            }
#pragma unroll
        for (int off = 1; off < 16; off <<= 1)
#pragma unroll
            for (int r = 0; r < 4; ++r) {
                ps[r] += __shfl_xor(ps[r], off);
                pd[r] += __shfl_xor(pd[r], off);
            }
        if (lm == 0) {
            int rb = row0 + i * 16 + (lane >> 4) * 4;
#pragma unroll
            for (int r = 0; r < 4; ++r) {
                if (rb + r < M) {
                    atomicAdd(&a_s[(rb + r) * 2 + head], ps[r]);
                    atomicAdd(&a_d[(rb + r) * 2 + head], pd[r]);
                }
            }
        }
#pragma unroll
        for (int j = 0; j < 4; ++j)
#pragma unroll
            for (int r = 0; r < 4; ++r) {
                int row = row0 + i * 16 + (lane >> 4) * 4 + r;
                if (row < M)
                    h16[(size_t)row * HCv + n0 + j * 16 + lm] = f2bf(acc[i][j][r]);
            }
    }
}

// ---------------- aggregation: one wave per destination node (R6 body) ----------------
// Max-free softmax; fused gather+exp pass; pass B at 4 edges/iter
// (quarter-wave x 2 uint4). Output always bf16 (both layers).

__device__ __forceinline__ float lrelu(float x) { return x > 0.f ? x : 0.2f * x; }

template <bool TANH>
__global__ __launch_bounds__(256) void agg_k(const unsigned short* __restrict__ h16,
                      const float* __restrict__ a_s, const float* __restrict__ a_d,
                      const int* __restrict__ start, const int* __restrict__ deg,
                      const int* __restrict__ colv, const float* __restrict__ bias,
                      unsigned short* __restrict__ out16) {
    __shared__ float lexp[4][MAXD][2];
    const int lane = threadIdx.x & 63;
    const int wslot = threadIdx.x >> 6;
    const int node = blockIdx.x * 4 + wslot;
    if (node >= N_NODES) return;
    const int beg = start[node];
    const int degv = deg[node];
    const float ad0 = a_d[node * 2], ad1 = a_d[node * 2 + 1];
    const int* __restrict__ col = colv + beg;

    if (degv <= MAXD) {
        // ---- pass A: gather a_s, exp (max-free), stash to LDS, sum ----
        float s0 = 0.f, s1 = 0.f;
        for (int j = lane; j < degv; j += 64) {
            int s = col[j];
            float2 av = *reinterpret_cast<const float2*>(a_s + s * 2);
            float e0 = __expf(lrelu(av.x + ad0));
            float e1 = __expf(lrelu(av.y + ad1));
            *reinterpret_cast<float2*>(&lexp[wslot][j][0]) = make_float2(e0, e1);
            s0 += e0;
            s1 += e1;
        }
#pragma unroll
        for (int off = 32; off; off >>= 1) {
            s0 += __shfl_xor(s0, off);
            s1 += __shfl_xor(s1, off);
        }
        const float inv0 = 1.f / (s0 + 1e-16f);
        const float inv1 = 1.f / (s1 + 1e-16f);

        // ---- pass B: 4 edges/iter; quarter q owns edge 4i+q; lane covers
        // 16 channels [lq*16, lq*16+16) (single head per lane) ----
        const int q = lane >> 4;
        const int lq = lane & 15;
        const int cb = lq * 16;
        const int head = lq >> 3;
        const float invh = head ? inv1 : inv0;
        const unsigned short* __restrict__ hp = h16 + cb;
        float acc[16] = {};
        const int full = degv >> 2;
        for (int i = 0; i < full; ++i) {
            const int j = 4 * i + q;
            const int s = col[j];
            const float alpha = lexp[wslot][j][head] * invh;
            const uint4* p = reinterpret_cast<const uint4*>(hp + (size_t)s * HCv);
            const uint4 h0 = p[0];
            const uint4 h1 = p[1];
            acc[0]  = fmaf(bf2f_lo(h0.x), alpha, acc[0]);
            acc[1]  = fmaf(bf2f_hi(h0.x), alpha, acc[1]);
            acc[2]  = fmaf(bf2f_lo(h0.y), alpha, acc[2]);
            acc[3]  = fmaf(bf2f_hi(h0.y), alpha, acc[3]);
            acc[4]  = fmaf(bf2f_lo(h0.z), alpha, acc[4]);
            acc[5]  = fmaf(bf2f_hi(h0.z), alpha, acc[5]);
            acc[6]  = fmaf(bf2f_lo(h0.w), alpha, acc[6]);
            acc[7]  = fmaf(bf2f_hi(h0.w), alpha, acc[7]);
            acc[8]  = fmaf(bf2f_lo(h1.x), alpha, acc[8]);
            acc[9]  = fmaf(bf2f_hi(h1.x), alpha, acc[9]);
            acc[10] = fmaf(bf2f_lo(h1.y), alpha, acc[10]);
            acc[11] = fmaf(bf2f_hi(h1.y), alpha, acc[11]);
            acc[12] = fmaf(bf2f_lo(h1.z), alpha, acc[12]);
            acc[13] = fmaf(bf2f_hi(h1.z), alpha, acc[13]);
            acc[14] = fmaf(bf2f_lo(h1.w), alpha, acc[14]);
            acc[15] = fmaf(bf2f_hi(h1.w), alpha, acc[15]);
        }
        {   // tail (degv & 3 edges)
            const int j = full * 4 + q;
            if (j < degv) {
                const int s = col[j];
                const float alpha = lexp[wslot][j][head] * invh;
                const uint4* p = reinterpret_cast<const uint4*>(hp + (size_t)s * HCv);
                const uint4 h0 = p[0];
                const uint4 h1 = p[1];
                acc[0]  = fmaf(bf2f_lo(h0.x), alpha, acc[0]);
                acc[1]  = fmaf(bf2f_hi(h0.x), alpha, acc[1]);
                acc[2]  = fmaf(bf2f_lo(h0.y), alpha, acc[2]);
                acc[3]  = fmaf(bf2f_hi(h0.y), alpha, acc[3]);
                acc[4]  = fmaf(bf2f_lo(h0.z), alpha, acc[4]);
                acc[5]  = fmaf(bf2f_hi(h0.z), alpha, acc[5]);
                acc[6]  = fmaf(bf2f_lo(h0.w), alpha, acc[6]);
                acc[7]  = fmaf(bf2f_hi(h0.w), alpha, acc[7]);
                acc[8]  = fmaf(bf2f_lo(h1.x), alpha, acc[8]);
                acc[9]  = fmaf(bf2f_hi(h1.x), alpha, acc[9]);
                acc[10] = fmaf(bf2f_lo(h1.y), alpha, acc[10]);
                acc[11] = fmaf(bf2f_hi(h1.y), alpha, acc[11]);
                acc[12] = fmaf(bf2f_lo(h1.z), alpha, acc[12]);
                acc[13] = fmaf(bf2f_hi(h1.z), alpha, acc[13]);
                acc[14] = fmaf(bf2f_lo(h1.w), alpha, acc[14]);
                acc[15] = fmaf(bf2f_hi(h1.w), alpha, acc[15]);
            }
        }
#pragma unroll
        for (int c = 0; c < 16; ++c) {
            acc[c] += __shfl_xor(acc[c], 16);
            acc[c] += __shfl_xor(acc[c], 32);
        }
        if (lane < 16) {
#pragma unroll
            for (int c = 0; c < 16; ++c) acc[c] += bias[cb + c];
            if (TANH) {
#pragma unroll
                for (int c = 0; c < 16; ++c) acc[c] = tanhf(acc[c]);
            }
            uint4 v0, v1;
            v0.x = f2bf_pack(acc[0], acc[1]);
            v0.y = f2bf_pack(acc[2], acc[3]);
            v0.z = f2bf_pack(acc[4], acc[5]);
            v0.w = f2bf_pack(acc[6], acc[7]);
            v1.x = f2bf_pack(acc[8], acc[9]);
            v1.y = f2bf_pack(acc[10], acc[11]);
            v1.z = f2bf_pack(acc[12], acc[13]);
            v1.w = f2bf_pack(acc[14], acc[15]);
            uint4* o = reinterpret_cast<uint4*>(out16 + (size_t)node * HCv + cb);
            o[0] = v0;
            o[1] = v1;
        }
    } else {
        // ---- fallback: 3-pass recompute path (deg > MAXD) ----
        const int end = beg + degv;
        float m0 = -INFINITY, m1 = -INFINITY;
        for (int e = beg + lane; e < end; e += 64) {
            int s = colv[e];
            m0 = fmaxf(m0, lrelu(a_s[s * 2] + ad0));
            m1 = fmaxf(m1, lrelu(a_s[s * 2 + 1] + ad1));
        }
#pragma unroll
        for (int off = 32; off; off >>= 1) {
            m0 = fmaxf(m0, __shfl_xor(m0, off));
            m1 = fmaxf(m1, __shfl_xor(m1, off));
        }
        float s0 = 0.f, s1 = 0.f;
        for (int e = beg + lane; e < end; e += 64) {
            int s = colv[e];
            s0 += __expf(lrelu(a_s[s * 2] + ad0) - m0);
            s1 += __expf(lrelu(a_s[s * 2 + 1] + ad1) - m1);
        }
#pragma unroll
        for (int off = 32; off; off >>= 1) {
            s0 += __shfl_xor(s0, off);
            s1 += __shfl_xor(s1, off);
        }
        float inv0 = 1.f / (s0 + 1e-16f);
        float inv1 = 1.f / (s1 + 1e-16f);
        const int head = lane >> 5;
        const float mh  = head ? m1 : m0;
        const float ih  = head ? inv1 : inv0;
        const float adh = head ? ad1 : ad0;
        const int cbase = lane * 4;
        float acc0 = 0.f, acc1 = 0.f, acc2 = 0.f, acc3 = 0.f;
        for (int e = beg; e < end; ++e) {
            int s = colv[e];
            float l = lrelu(a_s[s * 2 + head] + adh);
            float alpha = __expf(l - mh) * ih;
            uint2 hv = *reinterpret_cast<const uint2*>(h16 + (size_t)s * HCv + cbase);
            acc0 = fmaf(bf2f_lo(hv.x), alpha, acc0);
            acc1 = fmaf(bf2f_hi(hv.x), alpha, acc1);
            acc2 = fmaf(bf2f_lo(hv.y), alpha, acc2);
            acc3 = fmaf(bf2f_hi(hv.y), alpha, acc3);
        }
        float o0 = acc0 + bias[cbase + 0];
        float o1 = acc1 + bias[cbase + 1];
        float o2 = acc2 + bias[cbase + 2];
        float o3 = acc3 + bias[cbase + 3];
        if (TANH) {
            o0 = tanhf(o0); o1 = tanhf(o1); o2 = tanhf(o2); o3 = tanhf(o3);
        }
        ushort4 v;
        v.x = f2bf(o0); v.y = f2bf(o1); v.z = f2bf(o2); v.w = f2bf(o3);
        *reinterpret_cast<ushort4*>(out16 + (size_t)node * HCv + cbase) = v;
    }
}

// ---------------- final linear (256 -> 2) + softmax, bf16 input ----------------

__global__ void final_k(const unsigned short* __restrict__ h, const float* __restrict__ Wl,
                        const float* __restrict__ bl, float* __restrict__ out) {
    int lane = threadIdx.x & 63;
    int node = blockIdx.x * 4 + (threadIdx.x >> 6);
    if (node >= N_NODES) return;
    const int c = lane * 4;
    uint2 hv = *reinterpret_cast<const uint2*>(h + (size_t)node * HCv + c);
    float v0 = bf2f_lo(hv.x), v1 = bf2f_hi(hv.x);
    float v2 = bf2f_lo(hv.y), v3 = bf2f_hi(hv.y);
    float o0 = v0 * Wl[(c + 0) * 2 + 0] + v1 * Wl[(c + 1) * 2 + 0]
             + v2 * Wl[(c + 2) * 2 + 0] + v3 * Wl[(c + 3) * 2 + 0];
    float o1 = v0 * Wl[(c + 0) * 2 + 1] + v1 * Wl[(c + 1) * 2 + 1]
             + v2 * Wl[(c + 2) * 2 + 1] + v3 * Wl[(c + 3) * 2 + 1];
#pragma unroll
    for (int off = 32; off; off >>= 1) {
        o0 += __shfl_down(o0, off);
        o1 += __shfl_down(o1, off);
    }
    if (lane == 0) {
        o0 += bl[0];
        o1 += bl[1];
        float mx = fmaxf(o0, o1);
        float e0 = __expf(o0 - mx), e1 = __expf(o1 - mx);
        float inv = 1.f / (e0 + e1);
        out[node * 2 + 0] = e0 * inv;
        out[node * 2 + 1] = e1 * inv;
    }
}

// ---------------- launch ----------------

extern "C" void kernel_launch(void* const* d_in, const int* in_sizes, int n_in,
                              void* d_out, int out_size, void* d_ws, size_t ws_size,
                              hipStream_t stream) {
    const float* x        = (const float*)d_in[0];
    const int*   ei       = (const int*)d_in[1];
    const float* W0       = (const float*)d_in[2];
    const float* att_src0 = (const float*)d_in[3];
    const float* att_dst0 = (const float*)d_in[4];
    const float* b0       = (const float*)d_in[5];
    const float* W1       = (const float*)d_in[6];
    const float* att_src1 = (const float*)d_in[7];
    const float* att_dst1 = (const float*)d_in[8];
    const float* b1       = (const float*)d_in[9];
    const float* Wl       = (const float*)d_in[10];
    const float* bl       = (const float*)d_in[11];
    float* out = (float*)d_out;

    // workspace layout
    unsigned short* xb     = (unsigned short*)d_ws;               // N*128 bf16
    unsigned short* h16    = xb + (size_t)N_NODES * 128;          // N*256 bf16 (gemm out)
    unsigned short* hact16 = h16 + (size_t)N_NODES * HCv;         // N*256 bf16 (agg out)
    unsigned short* WT0    = hact16 + (size_t)N_NODES * HCv;      // 256*128 bf16
    unsigned short* WT1    = WT0 + 256 * 128;                     // 256*256 bf16
    float* a_s  = (float*)(WT1 + 256 * 256);                      // N*2
    float* a_d  = a_s + N_NODES * 2;                              // N*2
    int* deg    = (int*)(a_d + N_NODES * 2);                      // N
    int* total  = deg + N_NODES;                                  // 1
    int* start  = total + 1;                                      // N
    int* cursor = start + N_NODES;                                // N
    int* colv   = cursor + N_NODES;                               // E + N

    // ---- fused prep (cvt x, WT0/WT1, degree count, zero a_s/a_d) ----
    hipMemsetAsync(deg, 0, (N_NODES + 1) * sizeof(int), stream);  // deg + total
    prep_k<<<PREP_BLKS, 256, 0, stream>>>(x, xb, W0, WT0, W1, WT1, ei, deg, a_s);

    // ---- CSR offsets + scatter ----
    offsets_k<<<(N_NODES + 255) / 256, 256, 0, stream>>>(deg, start, cursor, total);
    scatter_k<<<(TOT_E + 255) / 256, 256, 0, stream>>>(ei, cursor, colv);

    dim3 ggrid(4, (N_NODES + 127) / 128);
    int nn4 = (N_NODES + 3) / 4;

    // ---- layer 0 ----
    mfma_gemm_att_k<128><<<ggrid, 256, 0, stream>>>(xb, WT0, h16, att_src0, att_dst0,
                                                    a_s, a_d, N_NODES);
    agg_k<true><<<nn4, 256, 0, stream>>>(h16, a_s, a_d, start, deg, colv, b0, hact16);

    // ---- layer 1 ----
    hipMemsetAsync(a_s, 0, (size_t)N_NODES * 4 * sizeof(float), stream);
    mfma_gemm_att_k<256><<<ggrid, 256, 0, stream>>>(hact16, WT1, h16, att_src1, att_dst1,
                                                    a_s, a_d, N_NODES);
    agg_k<false><<<nn4, 256, 0, stream>>>(h16, a_s, a_d, start, deg, colv, b1, hact16);

    // ---- final linear + softmax (bf16 input) ----
    final_k<<<nn4, 256, 0, stream>>>(hact16, Wl, bl, out);
}

// Round 10
// 336.329 us; speedup vs baseline: 1.0555x; 1.0009x over previous
//
#include <hip/hip_runtime.h>
#include <math.h>

// Problem constants (from reference)
constexpr int N_NODES = 50000;
constexpr int N_EDGES = 800000;
constexpr int TOT_E   = N_EDGES + N_NODES;   // + self loops
constexpr int HCv     = 256;                 // H*C
constexpr int MAXD    = 256;                 // LDS logit-cache capacity per wave

// GEMM grid geometry (XCD-swizzled 1-D launch; bid%8 == XCD round-robin)
constexpr int GY        = (N_NODES + 127) / 128;  // 391 row-tiles
constexpr int GPX       = (GY + 7) / 8;           // 49 row-tiles per XCD
constexpr int GEMM_BLKS = 8 * GPX * 4;            // 1568 (tail guarded)

// prep_k section sizes
constexpr int PREP_CVT   = (N_NODES * 128 / 4 + 255) / 256;   // 6250
constexpr int PREP_WT0   = 128;
constexpr int PREP_WT1   = 256;
constexpr int PREP_DEG   = (TOT_E + 255) / 256;               // 3321
constexpr int PREP_ZERO  = (N_NODES + 255) / 256;             // 196 (float4/thread)
constexpr int PREP_BLKS  = PREP_CVT + PREP_WT0 + PREP_WT1 + PREP_DEG + PREP_ZERO;

typedef __attribute__((ext_vector_type(8))) short bf16x8;
typedef __attribute__((ext_vector_type(4))) float f32x4;
typedef __attribute__((ext_vector_type(2))) float f32x2;

// ---- bf16 helpers (manual RNE, deterministic) ----
__device__ __forceinline__ unsigned short f2bf(float f) {
    unsigned int u = __float_as_uint(f);
    unsigned int r = (u + 0x7fffu + ((u >> 16) & 1u)) >> 16;
    return (unsigned short)r;
}
__device__ __forceinline__ unsigned int f2bf_pack(float lo, float hi) {
    return (unsigned int)f2bf(lo) | ((unsigned int)f2bf(hi) << 16);
}
__device__ __forceinline__ float bf2f_lo(unsigned int packed) {
    return __uint_as_float(packed << 16);
}
__device__ __forceinline__ float bf2f_hi(unsigned int packed) {
    return __uint_as_float(packed & 0xffff0000u);
}

// 8 bf16 channels += alpha * row-fragment, packed f32x2 (v_pk_fma_f32)
__device__ __forceinline__ void fma_row8_pk(const uint4 h, f32x2 al, f32x2* a2) {
    f32x2 p;
    p.x = bf2f_lo(h.x); p.y = bf2f_hi(h.x);
    a2[0] = __builtin_elementwise_fma(p, al, a2[0]);
    p.x = bf2f_lo(h.y); p.y = bf2f_hi(h.y);
    a2[1] = __builtin_elementwise_fma(p, al, a2[1]);
    p.x = bf2f_lo(h.z); p.y = bf2f_hi(h.z);
    a2[2] = __builtin_elementwise_fma(p, al, a2[2]);
    p.x = bf2f_lo(h.w); p.y = bf2f_hi(h.w);
    a2[3] = __builtin_elementwise_fma(p, al, a2[3]);
}

// ---------------- fused prep: cvt x, transpose W0/W1, count degrees, zero a_s/a_d ----

__global__ __launch_bounds__(256) void prep_k(const float* __restrict__ x,
                                              unsigned short* __restrict__ xb,
                                              const float* __restrict__ W0,
                                              unsigned short* __restrict__ WT0,
                                              const float* __restrict__ W1,
                                              unsigned short* __restrict__ WT1,
                                              const int* __restrict__ ei,
                                              int* __restrict__ deg,
                                              float* __restrict__ a_sd) {
    int b = blockIdx.x;
    if (b < PREP_CVT) {                       // x -> bf16 (float4 quads)
        int i = b * 256 + threadIdx.x;
        if (i < N_NODES * 128 / 4) {
            float4 v = *reinterpret_cast<const float4*>(x + (size_t)i * 4);
            ushort4 o;
            o.x = f2bf(v.x); o.y = f2bf(v.y); o.z = f2bf(v.z); o.w = f2bf(v.w);
            *reinterpret_cast<ushort4*>(xb + (size_t)i * 4) = o;
        }
        return;
    }
    b -= PREP_CVT;
    if (b < PREP_WT0) {                       // WT0[n][k] = bf16(W0[k][n]), K=128
        int idx = b * 256 + threadIdx.x;
        int k = idx >> 8, n = idx & 255;
        WT0[(size_t)n * 128 + k] = f2bf(W0[idx]);
        return;
    }
    b -= PREP_WT0;
    if (b < PREP_WT1) {                       // WT1[n][k] = bf16(W1[k][n]), K=256
        int idx = b * 256 + threadIdx.x;
        int k = idx >> 8, n = idx & 255;
        WT1[(size_t)n * 256 + k] = f2bf(W1[idx]);
        return;
    }
    b -= PREP_WT1;
    if (b < PREP_DEG) {                       // degree count
        int e = b * 256 + threadIdx.x;
        if (e < TOT_E) {
            int dst = (e < N_EDGES) ? ei[N_EDGES + e] : (e - N_EDGES);
            atomicAdd(&deg[dst], 1);
        }
        return;
    }
    b -= PREP_DEG;
    {                                         // zero a_s/a_d (N*4 floats)
        int i = b * 256 + threadIdx.x;
        if (i < N_NODES)
            *reinterpret_cast<float4*>(a_sd + (size_t)i * 4) = make_float4(0, 0, 0, 0);
    }
}

// ---------------- CSR build ----------------

__global__ void offsets_k(const int* __restrict__ deg, int* __restrict__ start,
                          int* __restrict__ cursor, int* __restrict__ total) {
    int lane = threadIdx.x & 63;
    int node = blockIdx.x * blockDim.x + threadIdx.x;
    int d = (node < N_NODES) ? deg[node] : 0;
    int pre = d;
#pragma unroll
    for (int off = 1; off < 64; off <<= 1) {
        int v = __shfl_up(pre, off);
        if (lane >= off) pre += v;
    }
    int wtot = __shfl(pre, 63);
    int base = 0;
    if (lane == 63) base = atomicAdd(total, wtot);
    base = __shfl(base, 63);
    int my = base + pre - d;
    if (node < N_NODES) { start[node] = my; cursor[node] = my; }
}

__global__ void scatter_k(const int* __restrict__ ei, int* __restrict__ cursor,
                          int* __restrict__ colv) {
    int e = blockIdx.x * blockDim.x + threadIdx.x;
    if (e >= TOT_E) return;
    int srcv, dstv;
    if (e < N_EDGES) { srcv = ei[e]; dstv = ei[N_EDGES + e]; }
    else             { srcv = dstv = e - N_EDGES; }
    int pos = atomicAdd(&cursor[dstv], 1);
    colv[pos] = srcv;
}

// ---------------- MFMA bf16 GEMM + fused attention epilogue ----------------
// XCD swizzle: all 4 col-blocks of one 128-row A-tile land on the SAME XCD
// (dispatch round-robins bid%8) -> A-tile refetch becomes same-L2 hits.

template <int K>
__global__ __launch_bounds__(256) void mfma_gemm_att_k(
        const unsigned short* __restrict__ A,   // [M][K] bf16
        const unsigned short* __restrict__ BT,  // [256][K] bf16 (W transposed)
        unsigned short* __restrict__ h16,       // [M][256] bf16 out
        const float* __restrict__ att_src, const float* __restrict__ att_dst,
        float* __restrict__ a_s, float* __restrict__ a_d, int M) {
    const int bid = blockIdx.x;
    const int xcd = bid & 7;
    const int t   = bid >> 3;
    const int kx  = t & 3;
    const int gy  = xcd + 8 * (t >> 2);
    if (gy >= GY) return;

    const int lane = threadIdx.x & 63;
    const int wv = threadIdx.x >> 6;
    const int lm = lane & 15;
    const int g8 = (lane >> 4) * 8;
    const int row0 = gy * 128 + wv * 32;
    const int n0 = kx * 64;

    int ra0 = row0 + lm;       if (ra0 >= M) ra0 = M - 1;
    int ra1 = row0 + 16 + lm;  if (ra1 >= M) ra1 = M - 1;
    const unsigned short* pa0 = A + (size_t)ra0 * K + g8;
    const unsigned short* pa1 = A + (size_t)ra1 * K + g8;
    const unsigned short* pb  = BT + (size_t)(n0 + lm) * K + g8;

    f32x4 acc[2][4] = {};
#pragma unroll
    for (int kt = 0; kt < K; kt += 32) {
        bf16x8 a0 = *reinterpret_cast<const bf16x8*>(pa0 + kt);
        bf16x8 a1 = *reinterpret_cast<const bf16x8*>(pa1 + kt);
        bf16x8 b0 = *reinterpret_cast<const bf16x8*>(pb + kt);
        bf16x8 b1 = *reinterpret_cast<const bf16x8*>(pb + 16 * K + kt);
        bf16x8 b2 = *reinterpret_cast<const bf16x8*>(pb + 32 * K + kt);
        bf16x8 b3 = *reinterpret_cast<const bf16x8*>(pb + 48 * K + kt);
        acc[0][0] = __builtin_amdgcn_mfma_f32_16x16x32_bf16(a0, b0, acc[0][0], 0, 0, 0);
        acc[0][1] = __builtin_amdgcn_mfma_f32_16x16x32_bf16(a0, b1, acc[0][1], 0, 0, 0);
        acc[0][2] = __builtin_amdgcn_mfma_f32_16x16x32_bf16(a0, b2, acc[0][2], 0, 0, 0);
        acc[0][3] = __builtin_amdgcn_mfma_f32_16x16x32_bf16(a0, b3, acc[0][3], 0, 0, 0);
        acc[1][0] = __builtin_amdgcn_mfma_f32_16x16x32_bf16(a1, b0, acc[1][0], 0, 0, 0);
        acc[1][1] = __builtin_amdgcn_mfma_f32_16x16x32_bf16(a1, b1, acc[1][1], 0, 0, 0);
        acc[1][2] = __builtin_amdgcn_mfma_f32_16x16x32_bf16(a1, b2, acc[1][2], 0, 0, 0);
        acc[1][3] = __builtin_amdgcn_mfma_f32_16x16x32_bf16(a1, b3, acc[1][3], 0, 0, 0);
    }

    float as_c[4], ad_c[4];
#pragma unroll
    for (int j = 0; j < 4; ++j) {
        int c = n0 + j * 16 + lm;
        as_c[j] = att_src[c];
        ad_c[j] = att_dst[c];
    }
    const int head = n0 >> 7;

#pragma unroll
    for (int i = 0; i < 2; ++i) {
        float ps[4] = {}, pd[4] = {};
#pragma unroll
        for (int j = 0; j < 4; ++j)
#pragma unroll
            for (int r = 0; r < 4; ++r) {
                ps[r] += acc[i][j][r] * as_c[j];
                pd[r] += acc[i][j][r] * ad_c[j];
            }
#pragma unroll
        for (int off = 1; off < 16; off <<= 1)
#pragma unroll
            for (int r = 0; r < 4; ++r) {
                ps[r] += __shfl_xor(ps[r], off);
                pd[r] += __shfl_xor(pd[r], off);
            }
        if (lm == 0) {
            int rb = row0 + i * 16 + (lane >> 4) * 4;
#pragma unroll
            for (int r = 0; r < 4; ++r) {
                if (rb + r < M) {
                    atomicAdd(&a_s[(rb + r) * 2 + head], ps[r]);
                    atomicAdd(&a_d[(rb + r) * 2 + head], pd[r]);
                }
            }
        }
#pragma unroll
        for (int j = 0; j < 4; ++j)
#pragma unroll
            for (int r = 0; r < 4; ++r) {
                int row = row0 + i * 16 + (lane >> 4) * 4 + r;
                if (row < M)
                    h16[(size_t)row * HCv + n0 + j * 16 + lm] = f2bf(acc[i][j][r]);
            }
    }
}

// ---------------- aggregation: one wave per destination node (R9 body + pk-fma) ----

__device__ __forceinline__ float lrelu(float x) { return x > 0.f ? x : 0.2f * x; }

template <bool TANH>
__global__ __launch_bounds__(256) void agg_k(const unsigned short* __restrict__ h16,
                      const float* __restrict__ a_s, const float* __restrict__ a_d,
                      const int* __restrict__ start, const int* __restrict__ deg,
                      const int* __restrict__ colv, const float* __restrict__ bias,
                      unsigned short* __restrict__ out16) {
    __shared__ float lexp[4][MAXD][2];
    const int lane = threadIdx.x & 63;
    const int wslot = threadIdx.x >> 6;
    const int node = blockIdx.x * 4 + wslot;
    if (node >= N_NODES) return;
    const int beg = start[node];
    const int degv = deg[node];
    const float ad0 = a_d[node * 2], ad1 = a_d[node * 2 + 1];
    const int* __restrict__ col = colv + beg;

    if (degv <= MAXD) {
        // ---- pass A: gather a_s, exp (max-free), stash to LDS, sum ----
        float s0 = 0.f, s1 = 0.f;
        for (int j = lane; j < degv; j += 64) {
            int s = col[j];
            float2 av = *reinterpret_cast<const float2*>(a_s + s * 2);
            float e0 = __expf(lrelu(av.x + ad0));
            float e1 = __expf(lrelu(av.y + ad1));
            *reinterpret_cast<float2*>(&lexp[wslot][j][0]) = make_float2(e0, e1);
            s0 += e0;
            s1 += e1;
        }
#pragma unroll
        for (int off = 32; off; off >>= 1) {
            s0 += __shfl_xor(s0, off);
            s1 += __shfl_xor(s1, off);
        }
        const float inv0 = 1.f / (s0 + 1e-16f);
        const float inv1 = 1.f / (s1 + 1e-16f);

        // ---- pass B: 4 edges/iter; quarter q owns edge 4i+q; lane covers
        // 16 channels [lq*16, lq*16+16); packed f32x2 accumulate ----
        const int q = lane >> 4;
        const int lq = lane & 15;
        const int cb = lq * 16;
        const int head = lq >> 3;
        const float invh = head ? inv1 : inv0;
        const unsigned short* __restrict__ hp = h16 + cb;
        f32x2 acc2[8] = {};
        const int full = degv >> 2;
        for (int i = 0; i < full; ++i) {
            const int j = 4 * i + q;
            const int s = col[j];
            const float alpha = lexp[wslot][j][head] * invh;
            const f32x2 al = {alpha, alpha};
            const uint4* p = reinterpret_cast<const uint4*>(hp + (size_t)s * HCv);
            const uint4 h0 = p[0];
            const uint4 h1 = p[1];
            fma_row8_pk(h0, al, acc2);
            fma_row8_pk(h1, al, acc2 + 4);
        }
        {   // tail (degv & 3 edges)
            const int j = full * 4 + q;
            if (j < degv) {
                const int s = col[j];
                const float alpha = lexp[wslot][j][head] * invh;
                const f32x2 al = {alpha, alpha};
                const uint4* p = reinterpret_cast<const uint4*>(hp + (size_t)s * HCv);
                const uint4 h0 = p[0];
                const uint4 h1 = p[1];
                fma_row8_pk(h0, al, acc2);
                fma_row8_pk(h1, al, acc2 + 4);
            }
        }
        float acc[16];
#pragma unroll
        for (int c = 0; c < 8; ++c) {
            acc[2 * c]     = acc2[c].x;
            acc[2 * c + 1] = acc2[c].y;
        }
#pragma unroll
        for (int c = 0; c < 16; ++c) {
            acc[c] += __shfl_xor(acc[c], 16);
            acc[c] += __shfl_xor(acc[c], 32);
        }
        if (lane < 16) {
#pragma unroll
            for (int c = 0; c < 16; ++c) acc[c] += bias[cb + c];
            if (TANH) {
#pragma unroll
                for (int c = 0; c < 16; ++c) acc[c] = tanhf(acc[c]);
            }
            uint4 v0, v1;
            v0.x = f2bf_pack(acc[0], acc[1]);
            v0.y = f2bf_pack(acc[2], acc[3]);
            v0.z = f2bf_pack(acc[4], acc[5]);
            v0.w = f2bf_pack(acc[6], acc[7]);
            v1.x = f2bf_pack(acc[8], acc[9]);
            v1.y = f2bf_pack(acc[10], acc[11]);
            v1.z = f2bf_pack(acc[12], acc[13]);
            v1.w = f2bf_pack(acc[14], acc[15]);
            uint4* o = reinterpret_cast<uint4*>(out16 + (size_t)node * HCv + cb);
            o[0] = v0;
            o[1] = v1;
        }
    } else {
        // ---- fallback: 3-pass recompute path (deg > MAXD) ----
        const int end = beg + degv;
        float m0 = -INFINITY, m1 = -INFINITY;
        for (int e = beg + lane; e < end; e += 64) {
            int s = colv[e];
            m0 = fmaxf(m0, lrelu(a_s[s * 2] + ad0));
            m1 = fmaxf(m1, lrelu(a_s[s * 2 + 1] + ad1));
        }
#pragma unroll
        for (int off = 32; off; off >>= 1) {
            m0 = fmaxf(m0, __shfl_xor(m0, off));
            m1 = fmaxf(m1, __shfl_xor(m1, off));
        }
        float s0 = 0.f, s1 = 0.f;
        for (int e = beg + lane; e < end; e += 64) {
            int s = colv[e];
            s0 += __expf(lrelu(a_s[s * 2] + ad0) - m0);
            s1 += __expf(lrelu(a_s[s * 2 + 1] + ad1) - m1);
        }
#pragma unroll
        for (int off = 32; off; off >>= 1) {
            s0 += __shfl_xor(s0, off);
            s1 += __shfl_xor(s1, off);
        }
        float inv0 = 1.f / (s0 + 1e-16f);
        float inv1 = 1.f / (s1 + 1e-16f);
        const int head = lane >> 5;
        const float mh  = head ? m1 : m0;
        const float ih  = head ? inv1 : inv0;
        const float adh = head ? ad1 : ad0;
        const int cbase = lane * 4;
        float acc0 = 0.f, acc1 = 0.f, acc2 = 0.f, acc3 = 0.f;
        for (int e = beg; e < end; ++e) {
            int s = colv[e];
            float l = lrelu(a_s[s * 2 + head] + adh);
            float alpha = __expf(l - mh) * ih;
            uint2 hv = *reinterpret_cast<const uint2*>(h16 + (size_t)s * HCv + cbase);
            acc0 = fmaf(bf2f_lo(hv.x), alpha, acc0);
            acc1 = fmaf(bf2f_hi(hv.x), alpha, acc1);
            acc2 = fmaf(bf2f_lo(hv.y), alpha, acc2);
            acc3 = fmaf(bf2f_hi(hv.y), alpha, acc3);
        }
        float o0 = acc0 + bias[cbase + 0];
        float o1 = acc1 + bias[cbase + 1];
        float o2 = acc2 + bias[cbase + 2];
        float o3 = acc3 + bias[cbase + 3];
        if (TANH) {
            o0 = tanhf(o0); o1 = tanhf(o1); o2 = tanhf(o2); o3 = tanhf(o3);
        }
        ushort4 v;
        v.x = f2bf(o0); v.y = f2bf(o1); v.z = f2bf(o2); v.w = f2bf(o3);
        *reinterpret_cast<ushort4*>(out16 + (size_t)node * HCv + cbase) = v;
    }
}

// ---------------- final linear (256 -> 2) + softmax, bf16 input ----------------

__global__ void final_k(const unsigned short* __restrict__ h, const float* __restrict__ Wl,
                        const float* __restrict__ bl, float* __restrict__ out) {
    int lane = threadIdx.x & 63;
    int node = blockIdx.x * 4 + (threadIdx.x >> 6);
    if (node >= N_NODES) return;
    const int c = lane * 4;
    uint2 hv = *reinterpret_cast<const uint2*>(h + (size_t)node * HCv + c);
    float v0 = bf2f_lo(hv.x), v1 = bf2f_hi(hv.x);
    float v2 = bf2f_lo(hv.y), v3 = bf2f_hi(hv.y);
    float o0 = v0 * Wl[(c + 0) * 2 + 0] + v1 * Wl[(c + 1) * 2 + 0]
             + v2 * Wl[(c + 2) * 2 + 0] + v3 * Wl[(c + 3) * 2 + 0];
    float o1 = v0 * Wl[(c + 0) * 2 + 1] + v1 * Wl[(c + 1) * 2 + 1]
             + v2 * Wl[(c + 2) * 2 + 1] + v3 * Wl[(c + 3) * 2 + 1];
#pragma unroll
    for (int off = 32; off; off >>= 1) {
        o0 += __shfl_down(o0, off);
        o1 += __shfl_down(o1, off);
    }
    if (lane == 0) {
        o0 += bl[0];
        o1 += bl[1];
        float mx = fmaxf(o0, o1);
        float e0 = __expf(o0 - mx), e1 = __expf(o1 - mx);
        float inv = 1.f / (e0 + e1);
        out[node * 2 + 0] = e0 * inv;
        out[node * 2 + 1] = e1 * inv;
    }
}

// ---------------- launch ----------------

extern "C" void kernel_launch(void* const* d_in, const int* in_sizes, int n_in,
                              void* d_out, int out_size, void* d_ws, size_t ws_size,
                              hipStream_t stream) {
    const float* x        = (const float*)d_in[0];
    const int*   ei       = (const int*)d_in[1];
    const float* W0       = (const float*)d_in[2];
    const float* att_src0 = (const float*)d_in[3];
    const float* att_dst0 = (const float*)d_in[4];
    const float* b0       = (const float*)d_in[5];
    const float* W1       = (const float*)d_in[6];
    const float* att_src1 = (const float*)d_in[7];
    const float* att_dst1 = (const float*)d_in[8];
    const float* b1       = (const float*)d_in[9];
    const float* Wl       = (const float*)d_in[10];
    const float* bl       = (const float*)d_in[11];
    float* out = (float*)d_out;

    // workspace layout
    unsigned short* xb     = (unsigned short*)d_ws;               // N*128 bf16
    unsigned short* h16    = xb + (size_t)N_NODES * 128;          // N*256 bf16 (gemm out)
    unsigned short* hact16 = h16 + (size_t)N_NODES * HCv;         // N*256 bf16 (agg out)
    unsigned short* WT0    = hact16 + (size_t)N_NODES * HCv;      // 256*128 bf16
    unsigned short* WT1    = WT0 + 256 * 128;                     // 256*256 bf16
    float* a_s  = (float*)(WT1 + 256 * 256);                      // N*2
    float* a_d  = a_s + N_NODES * 2;                              // N*2
    int* deg    = (int*)(a_d + N_NODES * 2);                      // N
    int* total  = deg + N_NODES;                                  // 1
    int* start  = total + 1;                                      // N
    int* cursor = start + N_NODES;                                // N
    int* colv   = cursor + N_NODES;                               // E + N

    // ---- fused prep (cvt x, WT0/WT1, degree count, zero a_s/a_d) ----
    hipMemsetAsync(deg, 0, (N_NODES + 1) * sizeof(int), stream);  // deg + total
    prep_k<<<PREP_BLKS, 256, 0, stream>>>(x, xb, W0, WT0, W1, WT1, ei, deg, a_s);

    // ---- CSR offsets + scatter ----
    offsets_k<<<(N_NODES + 255) / 256, 256, 0, stream>>>(deg, start, cursor, total);
    scatter_k<<<(TOT_E + 255) / 256, 256, 0, stream>>>(ei, cursor, colv);

    int nn4 = (N_NODES + 3) / 4;

    // ---- layer 0 ----
    mfma_gemm_att_k<128><<<GEMM_BLKS, 256, 0, stream>>>(xb, WT0, h16, att_src0, att_dst0,
                                                        a_s, a_d, N_NODES);
    agg_k<true><<<nn4, 256, 0, stream>>>(h16, a_s, a_d, start, deg, colv, b0, hact16);

    // ---- layer 1 ----
    hipMemsetAsync(a_s, 0, (size_t)N_NODES * 4 * sizeof(float), stream);
    mfma_gemm_att_k<256><<<GEMM_BLKS, 256, 0, stream>>>(hact16, WT1, h16, att_src1, att_dst1,
                                                        a_s, a_d, N_NODES);
    agg_k<false><<<nn4, 256, 0, stream>>>(h16, a_s, a_d, start, deg, colv, b1, hact16);

    // ---- final linear + softmax (bf16 input) ----
    final_k<<<nn4, 256, 0, stream>>>(hact16, Wl, bl, out);
}